// Round 17
// baseline (233.719 us; speedup 1.0000x reference)
//
#include <hip/hip_runtime.h>
#include <hip/hip_bf16.h>

// Problem constants: B=32768, IN=64, H=256, D=16, C=8, K=64, HS=8
// Output layout (floats, concatenated in return order):
#define O0 0ull          // K_chart   [32768]
#define O1 32768ull      // K_code    [32768]
#define O2 65536ull      // z_n       [32768][16]
#define O3 589824ull     // z_tex     [32768][16]
#define O4 1114112ull    // router_weights [32768][8]
#define O5 1376256ull    // z_geo     [32768][16]
#define O6 1900544ull    // vq_loss   [1]
#define O7 1900545ull    // indices   [32768][8]
#define O8 2162689ull    // z_n_all_charts [32768][8][16]
#define O9 6356993ull    // c_bar     [32768][16]

// ---------------------------------------------------------------------------
// Piecewise-Taylor erf: 64 intervals over [0, 4.27], degree-5 Horner,
// coefficient-major table (r15). Remainder <= ~3e-11.
// ---------------------------------------------------------------------------
static constexpr int    ENI  = 64;
static constexpr int    END  = 6;
static constexpr double EW   = 4.27 / 64.0;
static constexpr double EIW  = 64.0 / 4.27;

struct ErfTab { double a[END][ENI]; };   // [coeff][interval]

static constexpr double cexp_pos_(double x) {
    double s = 1.0, term = 1.0;
    for (int n = 1; n < 200; ++n) {
        term = term * x / (double)n;
        s += term;
        if (term < 1e-22 * s) break;
    }
    return s;
}
static constexpr ErfTab make_erftab_() {
    ErfTab T{};
    const double k2p = 1.12837916709551257390;
    double c0 = 0.5 * EW;
    double erf_cur = 0.0;
    {
        double u = c0 * c0, term = c0, s = 0.0;
        for (int n = 0; n < 40; ++n) { s += term / (double)(2 * n + 1); term *= -u / (double)(n + 1); }
        erf_cur = k2p * s;
    }
    const int NS = 24;
    for (int i = 0; i < ENI; ++i) {
        double c = ((double)i + 0.5) * EW;
        double e2 = k2p / cexp_pos_(c * c);
        double H[NS]; double a[NS + 1];
        H[0] = 1.0; H[1] = 2.0 * c;
        for (int n = 2; n < NS; ++n) H[n] = 2.0 * c * H[n - 1] - 2.0 * (double)(n - 1) * H[n - 2];
        a[0] = erf_cur;
        double fact = 1.0;
        for (int n = 1; n <= NS; ++n) {
            fact *= (double)n;
            double sgn = ((n - 1) & 1) ? -1.0 : 1.0;
            a[n] = sgn * H[n - 1] * e2 / fact;
        }
        for (int j = 0; j < END; ++j) T.a[j][i] = a[j];
        double s = 0.0, hp = 1.0;
        for (int n = 0; n <= NS; ++n) { s += a[n] * hp; hp *= EW; }
        erf_cur = s;
    }
    return T;
}
__constant__ ErfTab G_ERFTAB = make_erftab_();

__device__ __forceinline__ float erf_np_t(float t, const double* se) {
#pragma clang fp contract(off)
    double x = fabs((double)t);
    int idx = (int)(x * EIW);
    idx = idx > 63 ? 63 : idx;
    double d = x - ((double)idx + 0.5) * EW;
    double p = se[5 * 64 + idx];
    p = fma(p, d, se[4 * 64 + idx]);
    p = fma(p, d, se[3 * 64 + idx]);
    p = fma(p, d, se[2 * 64 + idx]);
    p = fma(p, d, se[1 * 64 + idx]);
    p = fma(p, d, se[0 * 64 + idx]);
    float e = (x >= 4.1) ? 1.0f : (float)p;
    return (t < 0.0f) ? -e : e;
}

__device__ __forceinline__ float4 gelu4_np(float4 z, const double* se) {
#pragma clang fp contract(off)
    const float s2 = 0x1.6a09e6p+0f;     // f32(sqrt(2))
    float4 r;
    float e0 = erf_np_t(z.x / s2, se);
    float e1 = erf_np_t(z.y / s2, se);
    float e2 = erf_np_t(z.z / s2, se);
    float e3 = erf_np_t(z.w / s2, se);
    r.x = (z.x * (e0 + 1.0f)) / 2.0f;
    r.y = (z.y * (e1 + 1.0f)) / 2.0f;
    r.z = (z.z * (e2 + 1.0f)) / 2.0f;
    r.w = (z.w * (e3 + 1.0f)) / 2.0f;
    return r;
}

// ---------------------------------------------------------------------------
// Fused MLP: v = (gelu(gelu(x@W1+b1)@W2+b2))@Wv + bv, np-f32 replica.
// 128 rows/block, 256 blocks (exactly 1/CU), 256 threads (4 waves x 32 rows).
// LDS 136 KB (ft[128][260] + erf table) -> 1 block/CU; each 4-k chunk in
// phase B = 4 weight float4 loads amortized over 512 FMA (~1024 cyc issue at
// 1 wave/SIMD) -- load latency hides under the FMA stream with 32-row ILP.
// Chip-wide L2 weight traffic: 256 MB (vs 512 MB at r16, 1 GB at r10).
// Every output keeps its ascending-k single-accumulator fmaf chain, bias
// after -> bit-identical outputs to rounds 4-16.
// ---------------------------------------------------------------------------
__global__ __launch_bounds__(256) void fused_mlp_np_k(
    const float* __restrict__ x,  const float* __restrict__ W1,
    const float* __restrict__ b1, const float* __restrict__ W2,
    const float* __restrict__ b2, const float* __restrict__ Wv,
    const float* __restrict__ bv, float* __restrict__ vout)
{
#pragma clang fp contract(off)
    __shared__ float  ft[128][260];      // 133.1 KB, pad 4 (float4-aligned)
    __shared__ double serf[ENI * END];   // 3 KB erf table (coeff-major)
    const int t  = threadIdx.x;
    const int w  = t >> 6;
    const int cg = t & 63;
    const int r0 = blockIdx.x * 128;
    const int rb = w * 32;               // wave's first row

    for (int i = t; i < ENI * END; i += 256) serf[i] = ((const double*)&G_ERFTAB)[i];
    __syncthreads();

    float acc[32][4];
#pragma unroll
    for (int i = 0; i < 32; ++i) { acc[i][0]=0.f; acc[i][1]=0.f; acc[i][2]=0.f; acc[i][3]=0.f; }

    // ---- phase A: f1 = gelu(x @ W1 + b1), K=64 ----
    for (int k0 = 0; k0 < 64; k0 += 4) {
        float4 w0 = *(const float4*)(W1 + (size_t)(k0 + 0) * 256 + cg * 4);
        float4 w1 = *(const float4*)(W1 + (size_t)(k0 + 1) * 256 + cg * 4);
        float4 w2 = *(const float4*)(W1 + (size_t)(k0 + 2) * 256 + cg * 4);
        float4 w3 = *(const float4*)(W1 + (size_t)(k0 + 3) * 256 + cg * 4);
#pragma unroll
        for (int rr = 0; rr < 32; ++rr) {
            float4 a = *(const float4*)(x + (size_t)(r0 + rb + rr) * 64 + k0);
            acc[rr][0] = fmaf(a.x, w0.x, acc[rr][0]);
            acc[rr][1] = fmaf(a.x, w0.y, acc[rr][1]);
            acc[rr][2] = fmaf(a.x, w0.z, acc[rr][2]);
            acc[rr][3] = fmaf(a.x, w0.w, acc[rr][3]);
            acc[rr][0] = fmaf(a.y, w1.x, acc[rr][0]);
            acc[rr][1] = fmaf(a.y, w1.y, acc[rr][1]);
            acc[rr][2] = fmaf(a.y, w1.z, acc[rr][2]);
            acc[rr][3] = fmaf(a.y, w1.w, acc[rr][3]);
            acc[rr][0] = fmaf(a.z, w2.x, acc[rr][0]);
            acc[rr][1] = fmaf(a.z, w2.y, acc[rr][1]);
            acc[rr][2] = fmaf(a.z, w2.z, acc[rr][2]);
            acc[rr][3] = fmaf(a.z, w2.w, acc[rr][3]);
            acc[rr][0] = fmaf(a.w, w3.x, acc[rr][0]);
            acc[rr][1] = fmaf(a.w, w3.y, acc[rr][1]);
            acc[rr][2] = fmaf(a.w, w3.z, acc[rr][2]);
            acc[rr][3] = fmaf(a.w, w3.w, acc[rr][3]);
        }
    }
    {
        float4 bb = *(const float4*)(b1 + cg * 4);
#pragma unroll
        for (int rr = 0; rr < 32; ++rr) {
            float4 z = make_float4(acc[rr][0] + bb.x, acc[rr][1] + bb.y,
                                   acc[rr][2] + bb.z, acc[rr][3] + bb.w);
            *(float4*)&ft[rb + rr][cg * 4] = gelu4_np(z, serf);
        }
    }
    // no barrier: each wave reads only its own 32 rows in phase B

    // ---- phase B: f2 = gelu(f1 @ W2 + b2), K=256 ----
#pragma unroll
    for (int i = 0; i < 32; ++i) { acc[i][0]=0.f; acc[i][1]=0.f; acc[i][2]=0.f; acc[i][3]=0.f; }
    for (int k0 = 0; k0 < 256; k0 += 4) {
        float4 w0 = *(const float4*)(W2 + (size_t)(k0 + 0) * 256 + cg * 4);
        float4 w1 = *(const float4*)(W2 + (size_t)(k0 + 1) * 256 + cg * 4);
        float4 w2 = *(const float4*)(W2 + (size_t)(k0 + 2) * 256 + cg * 4);
        float4 w3 = *(const float4*)(W2 + (size_t)(k0 + 3) * 256 + cg * 4);
#pragma unroll
        for (int rr = 0; rr < 32; ++rr) {
            float4 a = *(const float4*)&ft[rb + rr][k0];   // broadcast ds_read_b128
            acc[rr][0] = fmaf(a.x, w0.x, acc[rr][0]);
            acc[rr][1] = fmaf(a.x, w0.y, acc[rr][1]);
            acc[rr][2] = fmaf(a.x, w0.z, acc[rr][2]);
            acc[rr][3] = fmaf(a.x, w0.w, acc[rr][3]);
            acc[rr][0] = fmaf(a.y, w1.x, acc[rr][0]);
            acc[rr][1] = fmaf(a.y, w1.y, acc[rr][1]);
            acc[rr][2] = fmaf(a.y, w1.z, acc[rr][2]);
            acc[rr][3] = fmaf(a.y, w1.w, acc[rr][3]);
            acc[rr][0] = fmaf(a.z, w2.x, acc[rr][0]);
            acc[rr][1] = fmaf(a.z, w2.y, acc[rr][1]);
            acc[rr][2] = fmaf(a.z, w2.z, acc[rr][2]);
            acc[rr][3] = fmaf(a.z, w2.w, acc[rr][3]);
            acc[rr][0] = fmaf(a.w, w3.x, acc[rr][0]);
            acc[rr][1] = fmaf(a.w, w3.y, acc[rr][1]);
            acc[rr][2] = fmaf(a.w, w3.z, acc[rr][2]);
            acc[rr][3] = fmaf(a.w, w3.w, acc[rr][3]);
        }
    }
    {
        float4 bb = *(const float4*)(b2 + cg * 4);
#pragma unroll
        for (int rr = 0; rr < 32; ++rr) {
            float4 z = make_float4(acc[rr][0] + bb.x, acc[rr][1] + bb.y,
                                   acc[rr][2] + bb.z, acc[rr][3] + bb.w);
            *(float4*)&ft[rb + rr][cg * 4] = gelu4_np(z, serf);
        }
    }
    __syncthreads();   // phase C reads ft rows across waves

    // ---- phase C: v = f2 @ Wv + bv, 8 outputs per thread (128 rows x 16 d),
    //      ascending-k sequential fmaf chain per output ----
    {
        const int vrow = t & 127;
        const int d0   = (t >> 7) * 8;
        float a0 = 0.f, a1 = 0.f, a2 = 0.f, a3 = 0.f;
        float a4 = 0.f, a5 = 0.f, a6 = 0.f, a7 = 0.f;
        for (int k = 0; k < 256; ++k) {
            float f = ft[vrow][k];
            float4 qa = *(const float4*)(Wv + (size_t)k * 16 + d0);
            float4 qb = *(const float4*)(Wv + (size_t)k * 16 + d0 + 4);
            a0 = fmaf(f, qa.x, a0);  a1 = fmaf(f, qa.y, a1);
            a2 = fmaf(f, qa.z, a2);  a3 = fmaf(f, qa.w, a3);
            a4 = fmaf(f, qb.x, a4);  a5 = fmaf(f, qb.y, a5);
            a6 = fmaf(f, qb.z, a6);  a7 = fmaf(f, qb.w, a7);
        }
        float4 bva = *(const float4*)(bv + d0);
        float4 bvb = *(const float4*)(bv + d0 + 4);
        float* vp = vout + (size_t)(r0 + vrow) * 16 + d0;
        *(float4*)(vp)     = make_float4(a0 + bva.x, a1 + bva.y, a2 + bva.z, a3 + bva.w);
        *(float4*)(vp + 4) = make_float4(a4 + bvb.x, a5 + bvb.y, a6 + bvb.z, a7 + bvb.w);
    }
}

// ---------------------------------------------------------------------------
// Per-row atlas, np-f32 replica. thread=(row,chart), 32 rows/block.
// (unchanged from round 15)
// ---------------------------------------------------------------------------
__global__ __launch_bounds__(256) void atlas_np_k(
    const float* __restrict__ vbuf, const float* __restrict__ cc,
    const float* __restrict__ cb,   const float* __restrict__ sfW1,
    const float* __restrict__ sfb1, const float* __restrict__ sfW2,
    const float* __restrict__ sfb2, float* __restrict__ out,
    float* __restrict__ partials)
{
#pragma clang fp contract(off)
    __shared__ float scb[8448];       // union: codebook [8]x1032 / zql[32][132]+znl[32][132]
    __shared__ float scc[128];
    __shared__ float sW1[128];
    __shared__ float sW2[128];
    __shared__ float sb1[8];
    __shared__ float sb2[16];
    __shared__ float red[4];
    __shared__ double serf[ENI * END];

    const int t = threadIdx.x;
    for (int i = t; i < 8192; i += 256) {
        int c = i >> 10, rem = i & 1023, kk = rem >> 4, d = rem & 15;
        scb[c * 1032 + kk * 16 + d] = cb[i];
    }
    if (t < 128) { scc[t] = cc[t]; sW1[t] = sfW1[t]; sW2[t] = sfW2[t]; }
    if (t < 8)  sb1[t] = sfb1[t];
    if (t < 16) sb2[t] = sfb2[t];
    for (int i = t; i < ENI * END; i += 256) serf[i] = ((const double*)&G_ERFTAB)[i];
    __syncthreads();

    const int c    = t & 7;
    const int rloc = t >> 3;
    const int lane = t & 63;
    const int lb   = lane & ~7;
    const int row  = blockIdx.x * 32 + rloc;

    float v[16];
    {
        const float4* vp = (const float4*)(vbuf + (size_t)row * 16);
        float4 a = vp[0], b = vp[1], g = vp[2], h4 = vp[3];
        v[0]=a.x;  v[1]=a.y;  v[2]=a.z;  v[3]=a.w;
        v[4]=b.x;  v[5]=b.y;  v[6]=b.z;  v[7]=b.w;
        v[8]=g.x;  v[9]=g.y;  v[10]=g.z; v[11]=g.w;
        v[12]=h4.x; v[13]=h4.y; v[14]=h4.z; v[15]=h4.w;
    }

    // scores: sgemm k-seq fma over d, then /4 (exact)
    float score = 0.f;
#pragma unroll
    for (int d = 0; d < 16; ++d) score = fmaf(v[d], scc[c * 16 + d], score);
    score = score / 4.0f;

    // softmax: max (exact), exp via double downcast, pairwise-8 scalar-tree sum
    float m = score;
#pragma unroll
    for (int off = 1; off < 8; off <<= 1) m = fmaxf(m, __shfl_xor(m, off));
    float e = (float)exp((double)(score - m));
    float ea[8];
#pragma unroll
    for (int j = 0; j < 8; ++j) ea[j] = __shfl(e, lb + j);
    float s = ((ea[0] + ea[1]) + (ea[2] + ea[3])) + ((ea[4] + ea[5]) + (ea[6] + ea[7]));
    float rw = e / s;

    float rwa[8];
#pragma unroll
    for (int j = 0; j < 8; ++j) rwa[j] = ea[j] / s;

    // K_chart = np.argmax(router_weights): first-wins scan on f32 rw
    float bmv = rwa[0]; int bci = 0;
#pragma unroll
    for (int j = 1; j < 8; ++j) if (rwa[j] > bmv) { bmv = rwa[j]; bci = j; }

    // c_bar: sgemm K=8 seq fma; v_local f32 sub
    float cbar[16], vl[16];
#pragma unroll
    for (int d = 0; d < 16; ++d) {
        float a = 0.f;
#pragma unroll
        for (int j = 0; j < 8; ++j) a = fmaf(rwa[j], scc[j * 16 + d], a);
        cbar[d] = a;
        vl[d]   = v[d] - a;
    }

    // argmin over 64 codes: np dist = pairwise-16 scalar tree of (vl-q)^2, no fma
    const float* cbc = scb + c * 1032;
    float bd = 3.4e38f; int bk = 0; bool first = true;
    for (int kk = 0; kk < 64; ++kk) {
        const float4* q = (const float4*)(cbc + kk * 16);
        float4 q0 = q[0], q1 = q[1], q2 = q[2], q3 = q[3];
        float sq[16];
        float dd;
        dd = vl[0]  - q0.x; sq[0]  = dd * dd;
        dd = vl[1]  - q0.y; sq[1]  = dd * dd;
        dd = vl[2]  - q0.z; sq[2]  = dd * dd;
        dd = vl[3]  - q0.w; sq[3]  = dd * dd;
        dd = vl[4]  - q1.x; sq[4]  = dd * dd;
        dd = vl[5]  - q1.y; sq[5]  = dd * dd;
        dd = vl[6]  - q1.z; sq[6]  = dd * dd;
        dd = vl[7]  - q1.w; sq[7]  = dd * dd;
        dd = vl[8]  - q2.x; sq[8]  = dd * dd;
        dd = vl[9]  - q2.y; sq[9]  = dd * dd;
        dd = vl[10] - q2.z; sq[10] = dd * dd;
        dd = vl[11] - q2.w; sq[11] = dd * dd;
        dd = vl[12] - q3.x; sq[12] = dd * dd;
        dd = vl[13] - q3.y; sq[13] = dd * dd;
        dd = vl[14] - q3.z; sq[14] = dd * dd;
        dd = vl[15] - q3.w; sq[15] = dd * dd;
        float r0_ = sq[0] + sq[8],  r1_ = sq[1] + sq[9];
        float r2_ = sq[2] + sq[10], r3_ = sq[3] + sq[11];
        float r4_ = sq[4] + sq[12], r5_ = sq[5] + sq[13];
        float r6_ = sq[6] + sq[14], r7_ = sq[7] + sq[15];
        float dist = ((r0_ + r1_) + (r2_ + r3_)) + ((r4_ + r5_) + (r6_ + r7_));
        if (first || dist < bd) { bd = dist; bk = kk; first = false; }
    }

    float zq[16];
    {
        const float4* q = (const float4*)(cbc + bk * 16);
        float4 q0 = q[0], q1 = q[1], q2 = q[2], q3 = q[3];
        zq[0]=q0.x;  zq[1]=q0.y;  zq[2]=q0.z;  zq[3]=q0.w;
        zq[4]=q1.x;  zq[5]=q1.y;  zq[6]=q1.z;  zq[7]=q1.w;
        zq[8]=q2.x;  zq[9]=q2.y;  zq[10]=q2.z; zq[11]=q2.w;
        zq[12]=q3.x; zq[13]=q3.y; zq[14]=q3.z; zq[15]=q3.w;
    }

    float del[16];
#pragma unroll
    for (int d = 0; d < 16; ++d) del[d] = vl[d] - zq[d];

    // subnet: sgemm k-seq fma + bias-after + gelu_np (table, 4-wide)
    float pa[8];
#pragma unroll
    for (int j = 0; j < 8; ++j) {
        float a = 0.f;
#pragma unroll
        for (int d = 0; d < 16; ++d) a = fmaf(del[d], sW1[d * 8 + j], a);
        pa[j] = a + sb1[j];
    }
    float4 g0 = gelu4_np(make_float4(pa[0], pa[1], pa[2], pa[3]), serf);
    float4 g1 = gelu4_np(make_float4(pa[4], pa[5], pa[6], pa[7]), serf);
    float h[8] = { g0.x, g0.y, g0.z, g0.w, g1.x, g1.y, g1.z, g1.w };

    float zn[16];
#pragma unroll
    for (int d = 0; d < 16; ++d) {
        float a = 0.f;
#pragma unroll
        for (int j = 0; j < 8; ++j) a = fmaf(h[j], sW2[j * 16 + d], a);
        zn[d] = a + sb2[d];
    }

    // loss: rw * ||vl - zq||^2 (threshold loose; any order)
    float ls = 0.f;
#pragma unroll
    for (int d = 0; d < 16; ++d) ls = fmaf(del[d], del[d], ls);
    ls *= rw;

    // ---- cross-chart sums via LDS transpose (reuses scb; codebook dead now).
    // np sum over axis=1 = SEQUENTIAL over c ascending, products rounded first.
    __syncthreads();
    float* zql = scb;                      // [32][132]
    float* znl = scb + 4224;               // [32][132]
    {
        float* pq = zql + rloc * 132 + c * 16;
        float* pn = znl + rloc * 132 + c * 16;
        *(float4*)&pq[0]  = make_float4(zq[0],  zq[1],  zq[2],  zq[3]);
        *(float4*)&pq[4]  = make_float4(zq[4],  zq[5],  zq[6],  zq[7]);
        *(float4*)&pq[8]  = make_float4(zq[8],  zq[9],  zq[10], zq[11]);
        *(float4*)&pq[12] = make_float4(zq[12], zq[13], zq[14], zq[15]);
        *(float4*)&pn[0]  = make_float4(zn[0],  zn[1],  zn[2],  zn[3]);
        *(float4*)&pn[4]  = make_float4(zn[4],  zn[5],  zn[6],  zn[7]);
        *(float4*)&pn[8]  = make_float4(zn[8],  zn[9],  zn[10], zn[11]);
        *(float4*)&pn[12] = make_float4(zn[12], zn[13], zn[14], zn[15]);
    }
    __syncthreads();

    const int dd0 = c * 2;
    float aq0 = 0.f, aq1 = 0.f, an0 = 0.f, an1 = 0.f;
#pragma unroll
    for (int j = 0; j < 8; ++j) {          // ascending j, product-then-add (no fma)
        float2 qv = *(const float2*)&zql[rloc * 132 + j * 16 + dd0];
        float2 nv = *(const float2*)&znl[rloc * 132 + j * 16 + dd0];
        float p0 = qv.x * rwa[j]; aq0 = aq0 + p0;
        float p1 = qv.y * rwa[j]; aq1 = aq1 + p1;
        float p2 = nv.x * rwa[j]; an0 = an0 + p2;
        float p3 = nv.y * rwa[j]; an1 = an1 + p3;
    }

    // stores
    out[O4 + (size_t)row * 8 + c] = rw;
    out[O7 + (size_t)row * 8 + c] = (float)bk;
    {
        float* p = out + O8 + (size_t)row * 128 + c * 16;
#pragma unroll
        for (int d = 0; d < 16; ++d) p[d] = zn[d];
    }
    if (c == 0)   out[O0 + row] = (float)bci;
    if (c == bci) out[O1 + row] = (float)bk;
    {
        int d = dd0;
        float zst0 = vl[d]     + (aq0 - vl[d]);
        float zst1 = vl[d + 1] + (aq1 - vl[d + 1]);
        out[O2 + (size_t)row * 16 + d]     = an0;                        // z_n
        out[O2 + (size_t)row * 16 + d + 1] = an1;
        out[O3 + (size_t)row * 16 + d]     = (vl[d]     - aq0) - an0;    // z_tex
        out[O3 + (size_t)row * 16 + d + 1] = (vl[d + 1] - aq1) - an1;
        out[O5 + (size_t)row * 16 + d]     = (cbar[d]     + zst0) + an0; // z_geo
        out[O5 + (size_t)row * 16 + d + 1] = (cbar[d + 1] + zst1) + an1;
        out[O9 + (size_t)row * 16 + d]     = cbar[d];                    // c_bar
        out[O9 + (size_t)row * 16 + d + 1] = cbar[d + 1];
    }

    // block loss partial (deterministic)
#pragma unroll
    for (int off = 1; off < 64; off <<= 1) ls += __shfl_xor(ls, off);
    if ((t & 63) == 0) red[t >> 6] = ls;
    __syncthreads();
    if (t == 0) partials[blockIdx.x] = red[0] + red[1] + red[2] + red[3];
}

__global__ __launch_bounds__(256) void loss_reduce_k(
    const float* __restrict__ partials, float* __restrict__ out)
{
    __shared__ float sm[256];
    const int t = threadIdx.x;
    float a = 0.f;
    for (int i = t; i < 1024; i += 256) a += partials[i];
    sm[t] = a;
    __syncthreads();
    for (int s2 = 128; s2 > 0; s2 >>= 1) {
        if (t < s2) sm[t] += sm[t + s2];
        __syncthreads();
    }
    if (t == 0) out[O6] = sm[0] * (1.25f / 524288.0f);  // 1.25 / (B*D)
}

extern "C" void kernel_launch(void* const* d_in, const int* in_sizes, int n_in,
                              void* d_out, int out_size, void* d_ws, size_t ws_size,
                              hipStream_t stream) {
    (void)in_sizes; (void)n_in; (void)out_size;
    const float* x    = (const float*)d_in[0];
    const float* W1   = (const float*)d_in[1];
    const float* b1   = (const float*)d_in[2];
    const float* W2   = (const float*)d_in[3];
    const float* b2   = (const float*)d_in[4];
    const float* Wv   = (const float*)d_in[5];
    const float* bv   = (const float*)d_in[6];
    const float* cc   = (const float*)d_in[7];
    const float* cb   = (const float*)d_in[8];
    const float* sfW1 = (const float*)d_in[9];
    const float* sfb1 = (const float*)d_in[10];
    const float* sfW2 = (const float*)d_in[11];
    const float* sfb2 = (const float*)d_in[12];
    float* out = (float*)d_out;

    float* vbuf = (float*)d_ws;                       // [32768][16] f32 (2 MB)
    float* partials = vbuf + (size_t)32768 * 16;      // [1024]
    if (ws_size < ((size_t)32768 * 16 + 1024) * 4) return;

    fused_mlp_np_k<<<256, 256, 0, stream>>>(x, W1, b1, W2, b2, Wv, bv, vbuf);
    atlas_np_k    <<<1024, 256, 0, stream>>>(vbuf, cc, cb, sfW1, sfb1, sfW2, sfb2, out, partials);
    loss_reduce_k <<<1, 256, 0, stream>>>(partials, out);
}

// Round 18
// 137.678 us; speedup vs baseline: 1.6976x; 1.6976x over previous
//
#include <hip/hip_runtime.h>
#include <hip/hip_bf16.h>

// Problem constants: B=32768, IN=64, H=256, D=16, C=8, K=64, HS=8
// Output layout (floats, concatenated in return order):
#define O0 0ull          // K_chart   [32768]
#define O1 32768ull      // K_code    [32768]
#define O2 65536ull      // z_n       [32768][16]
#define O3 589824ull     // z_tex     [32768][16]
#define O4 1114112ull    // router_weights [32768][8]
#define O5 1376256ull    // z_geo     [32768][16]
#define O6 1900544ull    // vq_loss   [1]
#define O7 1900545ull    // indices   [32768][8]
#define O8 2162689ull    // z_n_all_charts [32768][8][16]
#define O9 6356993ull    // c_bar     [32768][16]

// ---------------------------------------------------------------------------
// Piecewise-Taylor erf: 64 intervals over [0, 4.27], degree-5 Horner,
// coefficient-major table. Remainder <= ~3e-11.
// ---------------------------------------------------------------------------
static constexpr int    ENI  = 64;
static constexpr int    END  = 6;
static constexpr double EW   = 4.27 / 64.0;
static constexpr double EIW  = 64.0 / 4.27;

struct ErfTab { double a[END][ENI]; };   // [coeff][interval]

static constexpr double cexp_pos_(double x) {
    double s = 1.0, term = 1.0;
    for (int n = 1; n < 200; ++n) {
        term = term * x / (double)n;
        s += term;
        if (term < 1e-22 * s) break;
    }
    return s;
}
static constexpr ErfTab make_erftab_() {
    ErfTab T{};
    const double k2p = 1.12837916709551257390;
    double c0 = 0.5 * EW;
    double erf_cur = 0.0;
    {
        double u = c0 * c0, term = c0, s = 0.0;
        for (int n = 0; n < 40; ++n) { s += term / (double)(2 * n + 1); term *= -u / (double)(n + 1); }
        erf_cur = k2p * s;
    }
    const int NS = 24;
    for (int i = 0; i < ENI; ++i) {
        double c = ((double)i + 0.5) * EW;
        double e2 = k2p / cexp_pos_(c * c);
        double H[NS]; double a[NS + 1];
        H[0] = 1.0; H[1] = 2.0 * c;
        for (int n = 2; n < NS; ++n) H[n] = 2.0 * c * H[n - 1] - 2.0 * (double)(n - 1) * H[n - 2];
        a[0] = erf_cur;
        double fact = 1.0;
        for (int n = 1; n <= NS; ++n) {
            fact *= (double)n;
            double sgn = ((n - 1) & 1) ? -1.0 : 1.0;
            a[n] = sgn * H[n - 1] * e2 / fact;
        }
        for (int j = 0; j < END; ++j) T.a[j][i] = a[j];
        double s = 0.0, hp = 1.0;
        for (int n = 0; n <= NS; ++n) { s += a[n] * hp; hp *= EW; }
        erf_cur = s;
    }
    return T;
}
__constant__ ErfTab G_ERFTAB = make_erftab_();

__device__ __forceinline__ float erf_np_t(float t, const double* se) {
#pragma clang fp contract(off)
    double x = fabs((double)t);
    int idx = (int)(x * EIW);
    idx = idx > 63 ? 63 : idx;
    double d = x - ((double)idx + 0.5) * EW;
    double p = se[5 * 64 + idx];
    p = fma(p, d, se[4 * 64 + idx]);
    p = fma(p, d, se[3 * 64 + idx]);
    p = fma(p, d, se[2 * 64 + idx]);
    p = fma(p, d, se[1 * 64 + idx]);
    p = fma(p, d, se[0 * 64 + idx]);
    float e = (x >= 4.1) ? 1.0f : (float)p;
    return (t < 0.0f) ? -e : e;
}

__device__ __forceinline__ float4 gelu4_np(float4 z, const double* se) {
#pragma clang fp contract(off)
    const float s2 = 0x1.6a09e6p+0f;     // f32(sqrt(2))
    float4 r;
    float e0 = erf_np_t(z.x / s2, se);
    float e1 = erf_np_t(z.y / s2, se);
    float e2 = erf_np_t(z.z / s2, se);
    float e3 = erf_np_t(z.w / s2, se);
    r.x = (z.x * (e0 + 1.0f)) / 2.0f;
    r.y = (z.y * (e1 + 1.0f)) / 2.0f;
    r.z = (z.z * (e2 + 1.0f)) / 2.0f;
    r.w = (z.w * (e3 + 1.0f)) / 2.0f;
    return r;
}

// ---------------------------------------------------------------------------
// Fused MLP: v = (gelu(gelu(x@W1+b1)@W2+b2))@Wv + bv, np-f32 replica.
// BEST MEASURED (r16): 64 rows/block, 512 blocks (2/CU), 256 threads
// (4 waves x 16 rows). Direct global weight reads; 16-row register tile is
// the intensity sweet spot (32 rows/thread spills: r17 = 238 us).
// Every output keeps its ascending-k single-accumulator fmaf chain, bias
// after -> bit-identical outputs to rounds 4-16.
// ---------------------------------------------------------------------------
__global__ __launch_bounds__(256) void fused_mlp_np_k(
    const float* __restrict__ x,  const float* __restrict__ W1,
    const float* __restrict__ b1, const float* __restrict__ W2,
    const float* __restrict__ b2, const float* __restrict__ Wv,
    const float* __restrict__ bv, float* __restrict__ vout)
{
#pragma clang fp contract(off)
    __shared__ float  ft[64][260];       // 66.6 KB, pad 4 (float4-aligned)
    __shared__ double serf[ENI * END];   // 3 KB erf table (coeff-major)
    const int t  = threadIdx.x;
    const int w  = t >> 6;
    const int cg = t & 63;
    const int r0 = blockIdx.x * 64;
    const int rb = w * 16;               // wave's first row

    for (int i = t; i < ENI * END; i += 256) serf[i] = ((const double*)&G_ERFTAB)[i];
    __syncthreads();

    float acc[16][4];
#pragma unroll
    for (int i = 0; i < 16; ++i) { acc[i][0]=0.f; acc[i][1]=0.f; acc[i][2]=0.f; acc[i][3]=0.f; }

    // ---- phase A: f1 = gelu(x @ W1 + b1), K=64 ----
    for (int k0 = 0; k0 < 64; k0 += 4) {
        float4 w0 = *(const float4*)(W1 + (size_t)(k0 + 0) * 256 + cg * 4);
        float4 w1 = *(const float4*)(W1 + (size_t)(k0 + 1) * 256 + cg * 4);
        float4 w2 = *(const float4*)(W1 + (size_t)(k0 + 2) * 256 + cg * 4);
        float4 w3 = *(const float4*)(W1 + (size_t)(k0 + 3) * 256 + cg * 4);
#pragma unroll
        for (int rr = 0; rr < 16; ++rr) {
            float4 a = *(const float4*)(x + (size_t)(r0 + rb + rr) * 64 + k0);
            acc[rr][0] = fmaf(a.x, w0.x, acc[rr][0]);
            acc[rr][1] = fmaf(a.x, w0.y, acc[rr][1]);
            acc[rr][2] = fmaf(a.x, w0.z, acc[rr][2]);
            acc[rr][3] = fmaf(a.x, w0.w, acc[rr][3]);
            acc[rr][0] = fmaf(a.y, w1.x, acc[rr][0]);
            acc[rr][1] = fmaf(a.y, w1.y, acc[rr][1]);
            acc[rr][2] = fmaf(a.y, w1.z, acc[rr][2]);
            acc[rr][3] = fmaf(a.y, w1.w, acc[rr][3]);
            acc[rr][0] = fmaf(a.z, w2.x, acc[rr][0]);
            acc[rr][1] = fmaf(a.z, w2.y, acc[rr][1]);
            acc[rr][2] = fmaf(a.z, w2.z, acc[rr][2]);
            acc[rr][3] = fmaf(a.z, w2.w, acc[rr][3]);
            acc[rr][0] = fmaf(a.w, w3.x, acc[rr][0]);
            acc[rr][1] = fmaf(a.w, w3.y, acc[rr][1]);
            acc[rr][2] = fmaf(a.w, w3.z, acc[rr][2]);
            acc[rr][3] = fmaf(a.w, w3.w, acc[rr][3]);
        }
    }
    {
        float4 bb = *(const float4*)(b1 + cg * 4);
#pragma unroll
        for (int rr = 0; rr < 16; ++rr) {
            float4 z = make_float4(acc[rr][0] + bb.x, acc[rr][1] + bb.y,
                                   acc[rr][2] + bb.z, acc[rr][3] + bb.w);
            *(float4*)&ft[rb + rr][cg * 4] = gelu4_np(z, serf);
        }
    }
    // no barrier: each wave reads only its own 16 rows in phase B

    // ---- phase B: f2 = gelu(f1 @ W2 + b2), K=256 ----
#pragma unroll
    for (int i = 0; i < 16; ++i) { acc[i][0]=0.f; acc[i][1]=0.f; acc[i][2]=0.f; acc[i][3]=0.f; }
    for (int k0 = 0; k0 < 256; k0 += 4) {
        float4 w0 = *(const float4*)(W2 + (size_t)(k0 + 0) * 256 + cg * 4);
        float4 w1 = *(const float4*)(W2 + (size_t)(k0 + 1) * 256 + cg * 4);
        float4 w2 = *(const float4*)(W2 + (size_t)(k0 + 2) * 256 + cg * 4);
        float4 w3 = *(const float4*)(W2 + (size_t)(k0 + 3) * 256 + cg * 4);
#pragma unroll
        for (int rr = 0; rr < 16; ++rr) {
            float4 a = *(const float4*)&ft[rb + rr][k0];   // broadcast ds_read_b128
            acc[rr][0] = fmaf(a.x, w0.x, acc[rr][0]);
            acc[rr][1] = fmaf(a.x, w0.y, acc[rr][1]);
            acc[rr][2] = fmaf(a.x, w0.z, acc[rr][2]);
            acc[rr][3] = fmaf(a.x, w0.w, acc[rr][3]);
            acc[rr][0] = fmaf(a.y, w1.x, acc[rr][0]);
            acc[rr][1] = fmaf(a.y, w1.y, acc[rr][1]);
            acc[rr][2] = fmaf(a.y, w1.z, acc[rr][2]);
            acc[rr][3] = fmaf(a.y, w1.w, acc[rr][3]);
            acc[rr][0] = fmaf(a.z, w2.x, acc[rr][0]);
            acc[rr][1] = fmaf(a.z, w2.y, acc[rr][1]);
            acc[rr][2] = fmaf(a.z, w2.z, acc[rr][2]);
            acc[rr][3] = fmaf(a.z, w2.w, acc[rr][3]);
            acc[rr][0] = fmaf(a.w, w3.x, acc[rr][0]);
            acc[rr][1] = fmaf(a.w, w3.y, acc[rr][1]);
            acc[rr][2] = fmaf(a.w, w3.z, acc[rr][2]);
            acc[rr][3] = fmaf(a.w, w3.w, acc[rr][3]);
        }
    }
    {
        float4 bb = *(const float4*)(b2 + cg * 4);
#pragma unroll
        for (int rr = 0; rr < 16; ++rr) {
            float4 z = make_float4(acc[rr][0] + bb.x, acc[rr][1] + bb.y,
                                   acc[rr][2] + bb.z, acc[rr][3] + bb.w);
            *(float4*)&ft[rb + rr][cg * 4] = gelu4_np(z, serf);
        }
    }
    __syncthreads();   // phase C reads ft rows across waves

    // ---- phase C: v = f2 @ Wv + bv, 4 outputs per thread (64 rows x 16 d),
    //      ascending-k sequential fmaf chain per output ----
    {
        const int vrow = t & 63;
        const int d0   = (t >> 6) * 4;
        float a0 = 0.f, a1 = 0.f, a2 = 0.f, a3 = 0.f;
        for (int k4 = 0; k4 < 256; k4 += 4) {
            float4 f = *(const float4*)&ft[vrow][k4];
            float4 q0 = *(const float4*)(Wv + (size_t)(k4 + 0) * 16 + d0);
            float4 q1 = *(const float4*)(Wv + (size_t)(k4 + 1) * 16 + d0);
            float4 q2 = *(const float4*)(Wv + (size_t)(k4 + 2) * 16 + d0);
            float4 q3 = *(const float4*)(Wv + (size_t)(k4 + 3) * 16 + d0);
            a0 = fmaf(f.x, q0.x, a0);  a1 = fmaf(f.x, q0.y, a1);
            a2 = fmaf(f.x, q0.z, a2);  a3 = fmaf(f.x, q0.w, a3);
            a0 = fmaf(f.y, q1.x, a0);  a1 = fmaf(f.y, q1.y, a1);
            a2 = fmaf(f.y, q1.z, a2);  a3 = fmaf(f.y, q1.w, a3);
            a0 = fmaf(f.z, q2.x, a0);  a1 = fmaf(f.z, q2.y, a1);
            a2 = fmaf(f.z, q2.z, a2);  a3 = fmaf(f.z, q2.w, a3);
            a0 = fmaf(f.w, q3.x, a0);  a1 = fmaf(f.w, q3.y, a1);
            a2 = fmaf(f.w, q3.z, a2);  a3 = fmaf(f.w, q3.w, a3);
        }
        float4 bvq = *(const float4*)(bv + d0);
        float4 o = make_float4(a0 + bvq.x, a1 + bvq.y, a2 + bvq.z, a3 + bvq.w);
        *(float4*)&vout[(size_t)(r0 + vrow) * 16 + d0] = o;
    }
}

// ---------------------------------------------------------------------------
// Per-row atlas, np-f32 replica. thread=(row,chart), 32 rows/block.
// ---------------------------------------------------------------------------
__global__ __launch_bounds__(256) void atlas_np_k(
    const float* __restrict__ vbuf, const float* __restrict__ cc,
    const float* __restrict__ cb,   const float* __restrict__ sfW1,
    const float* __restrict__ sfb1, const float* __restrict__ sfW2,
    const float* __restrict__ sfb2, float* __restrict__ out,
    float* __restrict__ partials)
{
#pragma clang fp contract(off)
    __shared__ float scb[8448];       // union: codebook [8]x1032 / zql[32][132]+znl[32][132]
    __shared__ float scc[128];
    __shared__ float sW1[128];
    __shared__ float sW2[128];
    __shared__ float sb1[8];
    __shared__ float sb2[16];
    __shared__ float red[4];
    __shared__ double serf[ENI * END];

    const int t = threadIdx.x;
    for (int i = t; i < 8192; i += 256) {
        int c = i >> 10, rem = i & 1023, kk = rem >> 4, d = rem & 15;
        scb[c * 1032 + kk * 16 + d] = cb[i];
    }
    if (t < 128) { scc[t] = cc[t]; sW1[t] = sfW1[t]; sW2[t] = sfW2[t]; }
    if (t < 8)  sb1[t] = sfb1[t];
    if (t < 16) sb2[t] = sfb2[t];
    for (int i = t; i < ENI * END; i += 256) serf[i] = ((const double*)&G_ERFTAB)[i];
    __syncthreads();

    const int c    = t & 7;
    const int rloc = t >> 3;
    const int lane = t & 63;
    const int lb   = lane & ~7;
    const int row  = blockIdx.x * 32 + rloc;

    float v[16];
    {
        const float4* vp = (const float4*)(vbuf + (size_t)row * 16);
        float4 a = vp[0], b = vp[1], g = vp[2], h4 = vp[3];
        v[0]=a.x;  v[1]=a.y;  v[2]=a.z;  v[3]=a.w;
        v[4]=b.x;  v[5]=b.y;  v[6]=b.z;  v[7]=b.w;
        v[8]=g.x;  v[9]=g.y;  v[10]=g.z; v[11]=g.w;
        v[12]=h4.x; v[13]=h4.y; v[14]=h4.z; v[15]=h4.w;
    }

    // scores: sgemm k-seq fma over d, then /4 (exact)
    float score = 0.f;
#pragma unroll
    for (int d = 0; d < 16; ++d) score = fmaf(v[d], scc[c * 16 + d], score);
    score = score / 4.0f;

    // softmax: max (exact), exp via double downcast, pairwise-8 scalar-tree sum
    float m = score;
#pragma unroll
    for (int off = 1; off < 8; off <<= 1) m = fmaxf(m, __shfl_xor(m, off));
    float e = (float)exp((double)(score - m));
    float ea[8];
#pragma unroll
    for (int j = 0; j < 8; ++j) ea[j] = __shfl(e, lb + j);
    float s = ((ea[0] + ea[1]) + (ea[2] + ea[3])) + ((ea[4] + ea[5]) + (ea[6] + ea[7]));
    float rw = e / s;

    float rwa[8];
#pragma unroll
    for (int j = 0; j < 8; ++j) rwa[j] = ea[j] / s;

    // K_chart = np.argmax(router_weights): first-wins scan on f32 rw
    float bmv = rwa[0]; int bci = 0;
#pragma unroll
    for (int j = 1; j < 8; ++j) if (rwa[j] > bmv) { bmv = rwa[j]; bci = j; }

    // c_bar: sgemm K=8 seq fma; v_local f32 sub
    float cbar[16], vl[16];
#pragma unroll
    for (int d = 0; d < 16; ++d) {
        float a = 0.f;
#pragma unroll
        for (int j = 0; j < 8; ++j) a = fmaf(rwa[j], scc[j * 16 + d], a);
        cbar[d] = a;
        vl[d]   = v[d] - a;
    }

    // argmin over 64 codes: np dist = pairwise-16 scalar tree of (vl-q)^2, no fma
    const float* cbc = scb + c * 1032;
    float bd = 3.4e38f; int bk = 0; bool first = true;
    for (int kk = 0; kk < 64; ++kk) {
        const float4* q = (const float4*)(cbc + kk * 16);
        float4 q0 = q[0], q1 = q[1], q2 = q[2], q3 = q[3];
        float sq[16];
        float dd;
        dd = vl[0]  - q0.x; sq[0]  = dd * dd;
        dd = vl[1]  - q0.y; sq[1]  = dd * dd;
        dd = vl[2]  - q0.z; sq[2]  = dd * dd;
        dd = vl[3]  - q0.w; sq[3]  = dd * dd;
        dd = vl[4]  - q1.x; sq[4]  = dd * dd;
        dd = vl[5]  - q1.y; sq[5]  = dd * dd;
        dd = vl[6]  - q1.z; sq[6]  = dd * dd;
        dd = vl[7]  - q1.w; sq[7]  = dd * dd;
        dd = vl[8]  - q2.x; sq[8]  = dd * dd;
        dd = vl[9]  - q2.y; sq[9]  = dd * dd;
        dd = vl[10] - q2.z; sq[10] = dd * dd;
        dd = vl[11] - q2.w; sq[11] = dd * dd;
        dd = vl[12] - q3.x; sq[12] = dd * dd;
        dd = vl[13] - q3.y; sq[13] = dd * dd;
        dd = vl[14] - q3.z; sq[14] = dd * dd;
        dd = vl[15] - q3.w; sq[15] = dd * dd;
        float r0_ = sq[0] + sq[8],  r1_ = sq[1] + sq[9];
        float r2_ = sq[2] + sq[10], r3_ = sq[3] + sq[11];
        float r4_ = sq[4] + sq[12], r5_ = sq[5] + sq[13];
        float r6_ = sq[6] + sq[14], r7_ = sq[7] + sq[15];
        float dist = ((r0_ + r1_) + (r2_ + r3_)) + ((r4_ + r5_) + (r6_ + r7_));
        if (first || dist < bd) { bd = dist; bk = kk; first = false; }
    }

    float zq[16];
    {
        const float4* q = (const float4*)(cbc + bk * 16);
        float4 q0 = q[0], q1 = q[1], q2 = q[2], q3 = q[3];
        zq[0]=q0.x;  zq[1]=q0.y;  zq[2]=q0.z;  zq[3]=q0.w;
        zq[4]=q1.x;  zq[5]=q1.y;  zq[6]=q1.z;  zq[7]=q1.w;
        zq[8]=q2.x;  zq[9]=q2.y;  zq[10]=q2.z; zq[11]=q2.w;
        zq[12]=q3.x; zq[13]=q3.y; zq[14]=q3.z; zq[15]=q3.w;
    }

    float del[16];
#pragma unroll
    for (int d = 0; d < 16; ++d) del[d] = vl[d] - zq[d];

    // subnet: sgemm k-seq fma + bias-after + gelu_np (table, 4-wide)
    float pa[8];
#pragma unroll
    for (int j = 0; j < 8; ++j) {
        float a = 0.f;
#pragma unroll
        for (int d = 0; d < 16; ++d) a = fmaf(del[d], sW1[d * 8 + j], a);
        pa[j] = a + sb1[j];
    }
    float4 g0 = gelu4_np(make_float4(pa[0], pa[1], pa[2], pa[3]), serf);
    float4 g1 = gelu4_np(make_float4(pa[4], pa[5], pa[6], pa[7]), serf);
    float h[8] = { g0.x, g0.y, g0.z, g0.w, g1.x, g1.y, g1.z, g1.w };

    float zn[16];
#pragma unroll
    for (int d = 0; d < 16; ++d) {
        float a = 0.f;
#pragma unroll
        for (int j = 0; j < 8; ++j) a = fmaf(h[j], sW2[j * 16 + d], a);
        zn[d] = a + sb2[d];
    }

    // loss: rw * ||vl - zq||^2 (threshold loose; any order)
    float ls = 0.f;
#pragma unroll
    for (int d = 0; d < 16; ++d) ls = fmaf(del[d], del[d], ls);
    ls *= rw;

    // ---- cross-chart sums via LDS transpose (reuses scb; codebook dead now).
    // np sum over axis=1 = SEQUENTIAL over c ascending, products rounded first.
    __syncthreads();
    float* zql = scb;                      // [32][132]
    float* znl = scb + 4224;               // [32][132]
    {
        float* pq = zql + rloc * 132 + c * 16;
        float* pn = znl + rloc * 132 + c * 16;
        *(float4*)&pq[0]  = make_float4(zq[0],  zq[1],  zq[2],  zq[3]);
        *(float4*)&pq[4]  = make_float4(zq[4],  zq[5],  zq[6],  zq[7]);
        *(float4*)&pq[8]  = make_float4(zq[8],  zq[9],  zq[10], zq[11]);
        *(float4*)&pq[12] = make_float4(zq[12], zq[13], zq[14], zq[15]);
        *(float4*)&pn[0]  = make_float4(zn[0],  zn[1],  zn[2],  zn[3]);
        *(float4*)&pn[4]  = make_float4(zn[4],  zn[5],  zn[6],  zn[7]);
        *(float4*)&pn[8]  = make_float4(zn[8],  zn[9],  zn[10], zn[11]);
        *(float4*)&pn[12] = make_float4(zn[12], zn[13], zn[14], zn[15]);
    }
    __syncthreads();

    const int dd0 = c * 2;
    float aq0 = 0.f, aq1 = 0.f, an0 = 0.f, an1 = 0.f;
#pragma unroll
    for (int j = 0; j < 8; ++j) {          // ascending j, product-then-add (no fma)
        float2 qv = *(const float2*)&zql[rloc * 132 + j * 16 + dd0];
        float2 nv = *(const float2*)&znl[rloc * 132 + j * 16 + dd0];
        float p0 = qv.x * rwa[j]; aq0 = aq0 + p0;
        float p1 = qv.y * rwa[j]; aq1 = aq1 + p1;
        float p2 = nv.x * rwa[j]; an0 = an0 + p2;
        float p3 = nv.y * rwa[j]; an1 = an1 + p3;
    }

    // stores
    out[O4 + (size_t)row * 8 + c] = rw;
    out[O7 + (size_t)row * 8 + c] = (float)bk;
    {
        float* p = out + O8 + (size_t)row * 128 + c * 16;
#pragma unroll
        for (int d = 0; d < 16; ++d) p[d] = zn[d];
    }
    if (c == 0)   out[O0 + row] = (float)bci;
    if (c == bci) out[O1 + row] = (float)bk;
    {
        int d = dd0;
        float zst0 = vl[d]     + (aq0 - vl[d]);
        float zst1 = vl[d + 1] + (aq1 - vl[d + 1]);
        out[O2 + (size_t)row * 16 + d]     = an0;                        // z_n
        out[O2 + (size_t)row * 16 + d + 1] = an1;
        out[O3 + (size_t)row * 16 + d]     = (vl[d]     - aq0) - an0;    // z_tex
        out[O3 + (size_t)row * 16 + d + 1] = (vl[d + 1] - aq1) - an1;
        out[O5 + (size_t)row * 16 + d]     = (cbar[d]     + zst0) + an0; // z_geo
        out[O5 + (size_t)row * 16 + d + 1] = (cbar[d + 1] + zst1) + an1;
        out[O9 + (size_t)row * 16 + d]     = cbar[d];                    // c_bar
        out[O9 + (size_t)row * 16 + d + 1] = cbar[d + 1];
    }

    // block loss partial (deterministic)
#pragma unroll
    for (int off = 1; off < 64; off <<= 1) ls += __shfl_xor(ls, off);
    if ((t & 63) == 0) red[t >> 6] = ls;
    __syncthreads();
    if (t == 0) partials[blockIdx.x] = red[0] + red[1] + red[2] + red[3];
}

__global__ __launch_bounds__(256) void loss_reduce_k(
    const float* __restrict__ partials, float* __restrict__ out)
{
    __shared__ float sm[256];
    const int t = threadIdx.x;
    float a = 0.f;
    for (int i = t; i < 1024; i += 256) a += partials[i];
    sm[t] = a;
    __syncthreads();
    for (int s2 = 128; s2 > 0; s2 >>= 1) {
        if (t < s2) sm[t] += sm[t + s2];
        __syncthreads();
    }
    if (t == 0) out[O6] = sm[0] * (1.25f / 524288.0f);  // 1.25 / (B*D)
}

extern "C" void kernel_launch(void* const* d_in, const int* in_sizes, int n_in,
                              void* d_out, int out_size, void* d_ws, size_t ws_size,
                              hipStream_t stream) {
    (void)in_sizes; (void)n_in; (void)out_size;
    const float* x    = (const float*)d_in[0];
    const float* W1   = (const float*)d_in[1];
    const float* b1   = (const float*)d_in[2];
    const float* W2   = (const float*)d_in[3];
    const float* b2   = (const float*)d_in[4];
    const float* Wv   = (const float*)d_in[5];
    const float* bv   = (const float*)d_in[6];
    const float* cc   = (const float*)d_in[7];
    const float* cb   = (const float*)d_in[8];
    const float* sfW1 = (const float*)d_in[9];
    const float* sfb1 = (const float*)d_in[10];
    const float* sfW2 = (const float*)d_in[11];
    const float* sfb2 = (const float*)d_in[12];
    float* out = (float*)d_out;

    float* vbuf = (float*)d_ws;                       // [32768][16] f32 (2 MB)
    float* partials = vbuf + (size_t)32768 * 16;      // [1024]
    if (ws_size < ((size_t)32768 * 16 + 1024) * 4) return;

    fused_mlp_np_k<<<512, 256, 0, stream>>>(x, W1, b1, W2, b2, Wv, bv, vbuf);
    atlas_np_k    <<<1024, 256, 0, stream>>>(vbuf, cc, cb, sfW1, sfb1, sfW2, sfb2, out, partials);
    loss_reduce_k <<<1, 256, 0, stream>>>(partials, out);
}